// Round 10
// baseline (116.066 us; speedup 1.0000x reference)
//
#include <hip/hip_runtime.h>

#define BB 16
#define HIMG 64
#define WIMG 64
#define CC 256
#define NHEAD 8
#define HD 32
#define NN 4096
#define PWD 65   // 2*DH+1
#define PADC 264 // qr_bf row stride (ushorts)
#define NCH 32   // k1 chunks per batch (128 rows each)

typedef short bf16x8 __attribute__((ext_vector_type(8)));
typedef float f32x4 __attribute__((ext_vector_type(4)));

__device__ __forceinline__ float elu1(float x) {
    return x > 0.0f ? x + 1.0f : __expf(x);
}
__device__ __forceinline__ float sigm(float x) {
    return 1.0f / (1.0f + __expf(-x));
}
__device__ __forceinline__ unsigned short f2bf(float f) {
    union { float f; unsigned int u; } v; v.f = f;
    unsigned int r = v.u + 0x7FFFu + ((v.u >> 16) & 1u);   // RNE
    return (unsigned short)(r >> 16);
}

// ---------------- Kernel 0: pw[n][c] = sigmoid(posw[i+1][j+1][c]) ---------------
__global__ __launch_bounds__(256) void k0_pw(
    const float* __restrict__ posw, float* __restrict__ pw)
{
    const int gid = blockIdx.x * 256 + threadIdx.x;  // 0 .. 262143
    const int n = gid >> 6;
    const int p = gid & 63;
    const int ii = n >> 6, jj = n & 63;
    const float4 v = *(const float4*)(posw + (size_t)((ii + 1) * PWD + (jj + 1)) * CC + p * 4);
    float4 r;
    r.x = sigm(v.x); r.y = sigm(v.y); r.z = sigm(v.z); r.w = sigm(v.w);
    *(float4*)(pw + (size_t)n * CC + p * 4) = r;
}

// ---------------- Kernel 1: partial kv + ksum — wave-independent, no LDS --------
// grid = 1024 blocks x 256 (4 waves). Wave gid -> (b, h, chunk of 128 rows).
// Lane (dq,eq) owns the 4x4 tile kv[dq*4..+4][eq*4..+4] of this head's 32x32 kv.
// Per row: 3 coalesced float4 loads (k, pw, v quads), 4 elu, 16 FMA. No barriers.
__global__ __launch_bounds__(256) void k1_partial(
    const float* __restrict__ x2, const float* __restrict__ x3,
    const float* __restrict__ pw, float* __restrict__ pkv,
    float* __restrict__ pksum)
{
    const int gid   = blockIdx.x * 4 + (threadIdx.x >> 6);  // 0..4095
    const int b     = gid >> 8;
    const int rem   = gid & 255;
    const int h     = rem >> 5;
    const int chunk = rem & 31;
    const int l     = threadIdx.x & 63;
    const int dq    = l >> 3;      // kr quad (d = dq*4..+4)
    const int eq    = l & 7;       // v  quad (e = eq*4..+4)
    const int n0    = chunk * 128;

    const float* pK = x2 + (size_t)b * NN * CC + (size_t)n0 * CC + h * HD + dq * 4;
    const float* pV = x3 + (size_t)b * NN * CC + (size_t)n0 * CC + h * HD + eq * 4;
    const float* pP = pw + (size_t)n0 * CC + h * HD + dq * 4;

    float acc[4][4];
#pragma unroll
    for (int a = 0; a < 4; ++a)
#pragma unroll
        for (int c = 0; c < 4; ++c) acc[a][c] = 0.0f;
    float ks[4] = {0.f, 0.f, 0.f, 0.f};

    for (int r = 0; r < 128; r += 4) {
        float4 kx[4], pv4[4], vx[4];
#pragma unroll
        for (int u = 0; u < 4; ++u)
            kx[u] = *(const float4*)(pK + (size_t)(r + u) * CC);
#pragma unroll
        for (int u = 0; u < 4; ++u)
            pv4[u] = *(const float4*)(pP + (size_t)(r + u) * CC);
#pragma unroll
        for (int u = 0; u < 4; ++u)
            vx[u] = *(const float4*)(pV + (size_t)(r + u) * CC);

#pragma unroll
        for (int u = 0; u < 4; ++u) {
            float k0 = elu1(kx[u].x), k1 = elu1(kx[u].y);
            float k2 = elu1(kx[u].z), k3 = elu1(kx[u].w);
            ks[0] += k0; ks[1] += k1; ks[2] += k2; ks[3] += k3;
            const float r0 = k0 * pv4[u].x, r1 = k1 * pv4[u].y;
            const float r2 = k2 * pv4[u].z, r3 = k3 * pv4[u].w;
            const float v0 = vx[u].x, v1 = vx[u].y, v2 = vx[u].z, v3 = vx[u].w;
            acc[0][0] = fmaf(r0, v0, acc[0][0]); acc[0][1] = fmaf(r0, v1, acc[0][1]);
            acc[0][2] = fmaf(r0, v2, acc[0][2]); acc[0][3] = fmaf(r0, v3, acc[0][3]);
            acc[1][0] = fmaf(r1, v0, acc[1][0]); acc[1][1] = fmaf(r1, v1, acc[1][1]);
            acc[1][2] = fmaf(r1, v2, acc[1][2]); acc[1][3] = fmaf(r1, v3, acc[1][3]);
            acc[2][0] = fmaf(r2, v0, acc[2][0]); acc[2][1] = fmaf(r2, v1, acc[2][1]);
            acc[2][2] = fmaf(r2, v2, acc[2][2]); acc[2][3] = fmaf(r2, v3, acc[2][3]);
            acc[3][0] = fmaf(r3, v0, acc[3][0]); acc[3][1] = fmaf(r3, v1, acc[3][1]);
            acc[3][2] = fmaf(r3, v2, acc[3][2]); acc[3][3] = fmaf(r3, v3, acc[3][3]);
        }
    }

    // pkv layout per (b*NCH+chunk): [8 heads][32 d][32 e]
    float* dst = pkv + (size_t)(b * NCH + chunk) * (NHEAD * HD * HD) + h * (HD * HD);
#pragma unroll
    for (int a = 0; a < 4; ++a) {
        float4 w4 = {acc[a][0], acc[a][1], acc[a][2], acc[a][3]};
        *(float4*)(dst + (dq * 4 + a) * HD + eq * 4) = w4;
    }
    if (eq == 0) {
        float* kd = pksum + (size_t)(b * NCH + chunk) * CC + h * HD + dq * 4;
        kd[0] = ks[0]; kd[1] = ks[1]; kd[2] = ks[2]; kd[3] = ks[3];
    }
}

// ---------------- Kernel 2: reduce partials; emit kvbT (bf16, [b][h][e][d]) -----
// grid = 512, block = 256
__global__ __launch_bounds__(256) void k2_reduce(
    const float* __restrict__ pkv, const float* __restrict__ pksum,
    unsigned short* __restrict__ kvbT, float* __restrict__ kmean)
{
    const int gid = blockIdx.x * 256 + threadIdx.x;   // over B*8192
    const int b = gid >> 13;
    const int o = gid & 8191;
    float s = 0.f;
#pragma unroll 4
    for (int c = 0; c < NCH; ++c)
        s += pkv[(size_t)(b * NCH + c) * (NHEAD * HD * HD) + o];
    const int hh = o >> 10, d = (o >> 5) & 31, e = o & 31;
    kvbT[(((size_t)b * NHEAD + hh) * HD + e) * HD + d] = f2bf(s * (1.0f / NN));
    if (o < CC) {
        float ss = 0.f;
#pragma unroll 4
        for (int c = 0; c < NCH; ++c)
            ss += pksum[(size_t)(b * NCH + c) * CC + o];
        kmean[b * CC + o] = ss * (1.0f / NN);
    }
}

// ---------------- Kernel 3: out = MFMA((qr*z) @ kv) + LePE ----------------------
// grid = B*256 (quarter image row each), block = 256 (4 waves)
__global__ __launch_bounds__(256, 2) void k3_out(
    const float* __restrict__ x1, const float* __restrict__ x3,
    const float* __restrict__ pw, const unsigned short* __restrict__ kvbT,
    const float* __restrict__ kmean, const float* __restrict__ lw,
    const float* __restrict__ lb, float* __restrict__ out)
{
    const int blk  = blockIdx.x;      // b*256 + irow*4 + jq
    const int b    = blk >> 8;
    const int irow = (blk >> 2) & 63;
    const int jq   = blk & 3;
    const int j0   = jq << 4;         // 0, 16, 32, 48
    const int t    = threadIdx.x;

    __shared__ unsigned short qr_bf[16 * PADC];   // (qr * z) in bf16, 8.4 KiB
    __shared__ float attn_lds[16][CC];            // 16 KiB

    float wreg[9];
#pragma unroll
    for (int q = 0; q < 9; ++q) wreg[q] = lw[t * 9 + q];
    const float bias = lb[t];

    // ---- stage: q_rope * z  -> bf16 LDS (z folded in; known after shfl reduce) ----
    {
        const int p    = t & 63;       // float4 slot within a pixel's 256 channels
        const int pixo = t >> 6;       // 0..3
        const float4 km4 = *(const float4*)(kmean + b * CC + p * 4);
        const float* x1b = x1 + ((size_t)b * NN + (size_t)irow * 64 + j0) * CC;
        const float* pwb = pw + ((size_t)irow * 64 + j0) * CC;
        float4 xv[4], pvv[4];
#pragma unroll
        for (int s = 0; s < 4; ++s)
            xv[s] = *(const float4*)(x1b + (size_t)(s * 4 + pixo) * CC + p * 4);
#pragma unroll
        for (int s = 0; s < 4; ++s)
            pvv[s] = *(const float4*)(pwb + (size_t)(s * 4 + pixo) * CC + p * 4);
#pragma unroll
        for (int s = 0; s < 4; ++s) {
            const int pix = s * 4 + pixo;   // 0..15 (local)
            float4 q4;
            q4.x = elu1(xv[s].x); q4.y = elu1(xv[s].y);
            q4.z = elu1(xv[s].z); q4.w = elu1(xv[s].w);
            float zp = q4.x * km4.x + q4.y * km4.y + q4.z * km4.z + q4.w * km4.w;
            zp += __shfl_xor(zp, 1);
            zp += __shfl_xor(zp, 2);
            zp += __shfl_xor(zp, 4);        // all 8 lanes of this head have the sum
            const float zin = 1.0f / (zp + 1e-6f);
            ushort4 u;
            u.x = f2bf(q4.x * pvv[s].x * zin);
            u.y = f2bf(q4.y * pvv[s].y * zin);
            u.z = f2bf(q4.z * pvv[s].z * zin);
            u.w = f2bf(q4.w * pvv[s].w * zin);
            *(ushort4*)(&qr_bf[pix * PADC + p * 4]) = u;
        }
    }

    // ---- halo loads issued BEFORE the barrier: cannot be sunk past it ----
    const bool hasU = irow > 0, hasD = irow < 63;
    const float* rU = x3 + ((size_t)b * NN + (size_t)(irow - 1) * 64 + j0) * CC + t;
    const float* rM = x3 + ((size_t)b * NN + (size_t)irow * 64 + j0) * CC + t;
    const float* rD = x3 + ((size_t)b * NN + (size_t)(irow + 1) * 64 + j0) * CC + t;

    float cu[2][10], cm[2][10], cd[2][10];
#pragma unroll
    for (int tt = 0; tt < 2; ++tt)
#pragma unroll
        for (int q = 0; q < 10; ++q) {
            const int col = tt * 8 + q - 1;     // local col in [-1, 16]
            const int g   = j0 + col;           // global col in [-1, 64]
            const bool ok = (g >= 0) && (g < 64);
            const long off = (long)col * CC;
            cm[tt][q] = ok ? rM[off] : 0.f;
            cu[tt][q] = (ok && hasU) ? rU[off] : 0.f;
            cd[tt][q] = (ok && hasD) ? rD[off] : 0.f;
        }

    __syncthreads();

    // ---- MFMA phase: wave w covers heads 2w,2w+1 over all 16 pixels ----
    {
        const int w  = t >> 6;
        const int l  = t & 63;
        const int lr = l & 15;     // A row (pixel) / B col / D col
        const int lg = l >> 4;     // k-group

        bf16x8 af0 = *(const bf16x8*)(&qr_bf[lr * PADC + (w * 2 + 0) * HD + lg * 8]);
        bf16x8 af1 = *(const bf16x8*)(&qr_bf[lr * PADC + (w * 2 + 1) * HD + lg * 8]);

        f32x4 acc[4];
#pragma unroll
        for (int ct = 0; ct < 4; ++ct) {
            const int head = w * 2 + (ct >> 1);
            const int cl   = (ct & 1) * 16 + lr;
            const bf16x8 bf = *(const bf16x8*)(kvbT +
                (((size_t)b * NHEAD + head) * HD + cl) * HD + lg * 8);
            f32x4 z4 = {0.f, 0.f, 0.f, 0.f};
            acc[ct] = __builtin_amdgcn_mfma_f32_16x16x32_bf16(
                (ct < 2) ? af0 : af1, bf, z4, 0, 0, 0);
        }
#pragma unroll
        for (int ct = 0; ct < 4; ++ct) {
            const int c = (w * 2 + (ct >> 1)) * HD + (ct & 1) * 16 + lr;
#pragma unroll
            for (int r = 0; r < 4; ++r)
                attn_lds[lg * 4 + r][c] = acc[ct][r];
        }
    }

    __syncthreads();

    // ---- epilogue: lepe (registers already loaded) + attn + store ----
    float* ob = out + ((size_t)b * NN + (size_t)irow * 64 + j0) * CC + t;
#pragma unroll
    for (int tt = 0; tt < 2; ++tt) {
#pragma unroll
        for (int q = 0; q < 8; ++q) {
            const int jl = tt * 8 + q;          // local pixel 0..15
            float lepe = bias
                + wreg[0] * cu[tt][q] + wreg[1] * cu[tt][q + 1] + wreg[2] * cu[tt][q + 2]
                + wreg[3] * cm[tt][q] + wreg[4] * cm[tt][q + 1] + wreg[5] * cm[tt][q + 2]
                + wreg[6] * cd[tt][q] + wreg[7] * cd[tt][q + 1] + wreg[8] * cd[tt][q + 2];
            __builtin_nontemporal_store(attn_lds[jl][t] + lepe, ob + (long)jl * CC);
        }
    }
}

extern "C" void kernel_launch(void* const* d_in, const int* in_sizes, int n_in,
                              void* d_out, int out_size, void* d_ws, size_t ws_size,
                              hipStream_t stream) {
    const float* x1   = (const float*)d_in[0];
    const float* x2   = (const float*)d_in[1];
    const float* x3   = (const float*)d_in[2];
    const float* posw = (const float*)d_in[3];
    const float* lw   = (const float*)d_in[4];
    const float* lb   = (const float*)d_in[5];
    float* out = (float*)d_out;

    // ws layout: pw | pkv | pksum | kmean | kvbT(ushort)  (~21.5 MB)
    const size_t pw_sz = (size_t)NN * CC;                   // 1M floats
    float* pwb   = (float*)d_ws;
    float* pkv   = pwb + pw_sz;                             // 16*NCH * 8192
    float* pksum = pkv + (size_t)16 * NCH * 8192;           // 16*NCH * 256
    float* kmean = pksum + (size_t)16 * NCH * 256;          // 16 * 256
    unsigned short* kvbT = (unsigned short*)(kmean + (size_t)16 * 256);  // 16*8192

    k0_pw<<<1024, 256, 0, stream>>>(posw, pwb);
    k1_partial<<<BB * NHEAD * NCH / 4, 256, 0, stream>>>(x2, x3, pwb, pkv, pksum);
    k2_reduce<<<512, 256, 0, stream>>>(pkv, pksum, kvbT, kmean);
    k3_out<<<BB * 256, 256, 0, stream>>>(x1, x3, pwb, kvbT, kmean, lw, lb, out);
}

// Round 11
// 88.875 us; speedup vs baseline: 1.3059x; 1.3059x over previous
//
#include <hip/hip_runtime.h>

#define BB 16
#define HIMG 64
#define WIMG 64
#define CC 256
#define NHEAD 8
#define HD 32
#define NN 4096
#define PWD 65   // 2*DH+1
#define PADC 264 // qr_bf row stride (ushorts)
#define NCH 32   // k1 chunks per batch (128 rows each)

typedef short bf16x8 __attribute__((ext_vector_type(8)));
typedef float f32x4 __attribute__((ext_vector_type(4)));

__device__ __forceinline__ float elu1(float x) {
    return x > 0.0f ? x + 1.0f : __expf(x);
}
__device__ __forceinline__ float sigm(float x) {
    return 1.0f / (1.0f + __expf(-x));
}
__device__ __forceinline__ unsigned short f2bf(float f) {
    union { float f; unsigned int u; } v; v.f = f;
    unsigned int r = v.u + 0x7FFFu + ((v.u >> 16) & 1u);   // RNE
    return (unsigned short)(r >> 16);
}

// ---------------- Kernel 0: pw[n][c] = sigmoid(posw[i+1][j+1][c]) ---------------
__global__ __launch_bounds__(256) void k0_pw(
    const float* __restrict__ posw, float* __restrict__ pw)
{
    const int gid = blockIdx.x * 256 + threadIdx.x;  // 0 .. 262143
    const int n = gid >> 6;
    const int p = gid & 63;
    const int ii = n >> 6, jj = n & 63;
    const float4 v = *(const float4*)(posw + (size_t)((ii + 1) * PWD + (jj + 1)) * CC + p * 4);
    float4 r;
    r.x = sigm(v.x); r.y = sigm(v.y); r.z = sigm(v.z); r.w = sigm(v.w);
    *(float4*)(pw + (size_t)n * CC + p * 4) = r;
}

// ---------------- Kernel 1: partial kv (K_rope^T V) and ksum per chunk ----------
// grid = 512 (b x chunk), block = 512 (8 waves). R5's proven ping-pong structure,
// scaled to 8 waves/block: waves 0-3 load k+pw, waves 4-7 load v (1KB coalesced),
// 8-row steps, one __syncthreads per step, 2 blocks/CU all-resident (16 waves/CU).
__global__ __launch_bounds__(512, 4) void k1_partial(
    const float* __restrict__ x2, const float* __restrict__ x3,
    const float* __restrict__ pw, float* __restrict__ pkv,
    float* __restrict__ pksum)
{
    const int blk   = blockIdx.x;          // b*NCH + chunk
    const int b     = blk >> 5;
    const int chunk = blk & 31;
    const int n0    = chunk * 128;
    const int t     = threadIdx.x;
    const bool isK  = t < 256;
    const int rbase = (t & 255) >> 6;      // 0..3 (row group)
    const int slot  = t & 63;              // float4 slot within a row

    const int h  = t >> 6;                 // compute: head 0..7 (one wave per head)
    const int l  = t & 63;
    const int dq = l >> 3;                 // d-quad
    const int eq = l & 7;                  // e-quad

    __shared__ float kr_lds[2][8][CC];     // 16 KiB
    __shared__ float v_lds[2][8][CC];      // 16 KiB
    __shared__ float ksum_lds[4][CC];      // 4 KiB

    float acc[4][4];
#pragma unroll
    for (int a = 0; a < 4; ++a)
#pragma unroll
        for (int c = 0; c < 4; ++c) acc[a][c] = 0.0f;
    float ks0 = 0.f, ks1 = 0.f, ks2 = 0.f, ks3 = 0.f;

    const float* x2b = x2 + (size_t)b * NN * CC;
    const float* x3b = x3 + (size_t)b * NN * CC;

    float4 kx[2], pv[2], vx[2];

#define K1_LOAD(sS)                                                           \
    do {                                                                      \
        const int r0_ = n0 + (sS) * 8;                                        \
        if (isK) {                                                            \
            _Pragma("unroll")                                                 \
            for (int it_ = 0; it_ < 2; ++it_) {                               \
                const int n_ = r0_ + rbase + 4 * it_;                         \
                kx[it_] = *(const float4*)(x2b + (size_t)n_ * CC + slot * 4); \
            }                                                                 \
            _Pragma("unroll")                                                 \
            for (int it_ = 0; it_ < 2; ++it_) {                               \
                const int n_ = r0_ + rbase + 4 * it_;                         \
                pv[it_] = *(const float4*)(pw + (size_t)n_ * CC + slot * 4);  \
            }                                                                 \
        } else {                                                              \
            _Pragma("unroll")                                                 \
            for (int it_ = 0; it_ < 2; ++it_) {                               \
                const int n_ = r0_ + rbase + 4 * it_;                         \
                vx[it_] = *(const float4*)(x3b + (size_t)n_ * CC + slot * 4); \
            }                                                                 \
        }                                                                     \
    } while (0)

    K1_LOAD(0);
    int buf = 0;
    for (int s = 0; s < 16; ++s) {
        // ---- write current regs to LDS[buf] ----
        if (isK) {
#pragma unroll
            for (int it = 0; it < 2; ++it) {
                const int row = rbase + 4 * it;
                float k0 = elu1(kx[it].x), k1 = elu1(kx[it].y);
                float k2 = elu1(kx[it].z), k3 = elu1(kx[it].w);
                ks0 += k0; ks1 += k1; ks2 += k2; ks3 += k3;
                float4 kr;
                kr.x = k0 * pv[it].x; kr.y = k1 * pv[it].y;
                kr.z = k2 * pv[it].z; kr.w = k3 * pv[it].w;
                *(float4*)(&kr_lds[buf][row][slot * 4]) = kr;
            }
        } else {
#pragma unroll
            for (int it = 0; it < 2; ++it)
                *(float4*)(&v_lds[buf][rbase + 4 * it][slot * 4]) = vx[it];
        }
        __syncthreads();
        // ---- issue loads for step s+1 (in flight during compute) ----
        if (s + 1 < 16) K1_LOAD(s + 1);
        // ---- compute from LDS[buf]: wave h, lane (dq,eq): 4x4 tile ----
#pragma unroll
        for (int r = 0; r < 8; ++r) {
            const float4 k4 = *(const float4*)(&kr_lds[buf][r][h * HD + dq * 4]);
            const float4 v4 = *(const float4*)(&v_lds[buf][r][h * HD + eq * 4]);
            const float kd[4] = {k4.x, k4.y, k4.z, k4.w};
            const float ve[4] = {v4.x, v4.y, v4.z, v4.w};
#pragma unroll
            for (int a = 0; a < 4; ++a)
#pragma unroll
                for (int c = 0; c < 4; ++c)
                    acc[a][c] = fmaf(kd[a], ve[c], acc[a][c]);
        }
        buf ^= 1;
    }
#undef K1_LOAD

    if (isK) {
        ksum_lds[rbase][slot * 4 + 0] = ks0;
        ksum_lds[rbase][slot * 4 + 1] = ks1;
        ksum_lds[rbase][slot * 4 + 2] = ks2;
        ksum_lds[rbase][slot * 4 + 3] = ks3;
    }
    __syncthreads();
    if (t < CC) {
        pksum[(size_t)blk * CC + t] = ksum_lds[0][t] + ksum_lds[1][t] +
                                      ksum_lds[2][t] + ksum_lds[3][t];
    }

    // pkv layout per blk: [8 heads][32 d][32 e]
    float* dst = pkv + (size_t)blk * (NHEAD * HD * HD) + h * (HD * HD);
#pragma unroll
    for (int a = 0; a < 4; ++a) {
        float4 w4 = {acc[a][0], acc[a][1], acc[a][2], acc[a][3]};
        *(float4*)(dst + (dq * 4 + a) * HD + eq * 4) = w4;
    }
}

// ---------------- Kernel 2: reduce partials; emit kvbT (bf16, [b][h][e][d]) -----
// grid = 512, block = 256
__global__ __launch_bounds__(256) void k2_reduce(
    const float* __restrict__ pkv, const float* __restrict__ pksum,
    unsigned short* __restrict__ kvbT, float* __restrict__ kmean)
{
    const int gid = blockIdx.x * 256 + threadIdx.x;   // over B*8192
    const int b = gid >> 13;
    const int o = gid & 8191;
    float s = 0.f;
#pragma unroll 4
    for (int c = 0; c < NCH; ++c)
        s += pkv[(size_t)(b * NCH + c) * (NHEAD * HD * HD) + o];
    const int hh = o >> 10, d = (o >> 5) & 31, e = o & 31;
    kvbT[(((size_t)b * NHEAD + hh) * HD + e) * HD + d] = f2bf(s * (1.0f / NN));
    if (o < CC) {
        float ss = 0.f;
#pragma unroll 4
        for (int c = 0; c < NCH; ++c)
            ss += pksum[(size_t)(b * NCH + c) * CC + o];
        kmean[b * CC + o] = ss * (1.0f / NN);
    }
}

// ---------------- Kernel 3: out = MFMA((qr*z) @ kv) + LePE ----------------------
// grid = B*256 (quarter image row each), block = 256 (4 waves)
__global__ __launch_bounds__(256, 2) void k3_out(
    const float* __restrict__ x1, const float* __restrict__ x3,
    const float* __restrict__ pw, const unsigned short* __restrict__ kvbT,
    const float* __restrict__ kmean, const float* __restrict__ lw,
    const float* __restrict__ lb, float* __restrict__ out)
{
    const int blk  = blockIdx.x;      // b*256 + irow*4 + jq
    const int b    = blk >> 8;
    const int irow = (blk >> 2) & 63;
    const int jq   = blk & 3;
    const int j0   = jq << 4;         // 0, 16, 32, 48
    const int t    = threadIdx.x;

    __shared__ unsigned short qr_bf[16 * PADC];   // (qr * z) in bf16, 8.4 KiB
    __shared__ float attn_lds[16][CC];            // 16 KiB

    float wreg[9];
#pragma unroll
    for (int q = 0; q < 9; ++q) wreg[q] = lw[t * 9 + q];
    const float bias = lb[t];

    // ---- stage: q_rope * z  -> bf16 LDS (z folded in; known after shfl reduce) ----
    {
        const int p    = t & 63;       // float4 slot within a pixel's 256 channels
        const int pixo = t >> 6;       // 0..3
        const float4 km4 = *(const float4*)(kmean + b * CC + p * 4);
        const float* x1b = x1 + ((size_t)b * NN + (size_t)irow * 64 + j0) * CC;
        const float* pwb = pw + ((size_t)irow * 64 + j0) * CC;
        float4 xv[4], pvv[4];
#pragma unroll
        for (int s = 0; s < 4; ++s)
            xv[s] = *(const float4*)(x1b + (size_t)(s * 4 + pixo) * CC + p * 4);
#pragma unroll
        for (int s = 0; s < 4; ++s)
            pvv[s] = *(const float4*)(pwb + (size_t)(s * 4 + pixo) * CC + p * 4);
#pragma unroll
        for (int s = 0; s < 4; ++s) {
            const int pix = s * 4 + pixo;   // 0..15 (local)
            float4 q4;
            q4.x = elu1(xv[s].x); q4.y = elu1(xv[s].y);
            q4.z = elu1(xv[s].z); q4.w = elu1(xv[s].w);
            float zp = q4.x * km4.x + q4.y * km4.y + q4.z * km4.z + q4.w * km4.w;
            zp += __shfl_xor(zp, 1);
            zp += __shfl_xor(zp, 2);
            zp += __shfl_xor(zp, 4);        // all 8 lanes of this head have the sum
            const float zin = 1.0f / (zp + 1e-6f);
            ushort4 u;
            u.x = f2bf(q4.x * pvv[s].x * zin);
            u.y = f2bf(q4.y * pvv[s].y * zin);
            u.z = f2bf(q4.z * pvv[s].z * zin);
            u.w = f2bf(q4.w * pvv[s].w * zin);
            *(ushort4*)(&qr_bf[pix * PADC + p * 4]) = u;
        }
    }

    // ---- halo loads issued BEFORE the barrier: cannot be sunk past it ----
    const bool hasU = irow > 0, hasD = irow < 63;
    const float* rU = x3 + ((size_t)b * NN + (size_t)(irow - 1) * 64 + j0) * CC + t;
    const float* rM = x3 + ((size_t)b * NN + (size_t)irow * 64 + j0) * CC + t;
    const float* rD = x3 + ((size_t)b * NN + (size_t)(irow + 1) * 64 + j0) * CC + t;

    float cu[2][10], cm[2][10], cd[2][10];
#pragma unroll
    for (int tt = 0; tt < 2; ++tt)
#pragma unroll
        for (int q = 0; q < 10; ++q) {
            const int col = tt * 8 + q - 1;     // local col in [-1, 16]
            const int g   = j0 + col;           // global col in [-1, 64]
            const bool ok = (g >= 0) && (g < 64);
            const long off = (long)col * CC;
            cm[tt][q] = ok ? rM[off] : 0.f;
            cu[tt][q] = (ok && hasU) ? rU[off] : 0.f;
            cd[tt][q] = (ok && hasD) ? rD[off] : 0.f;
        }

    __syncthreads();

    // ---- MFMA phase: wave w covers heads 2w,2w+1 over all 16 pixels ----
    {
        const int w  = t >> 6;
        const int l  = t & 63;
        const int lr = l & 15;     // A row (pixel) / B col / D col
        const int lg = l >> 4;     // k-group

        bf16x8 af0 = *(const bf16x8*)(&qr_bf[lr * PADC + (w * 2 + 0) * HD + lg * 8]);
        bf16x8 af1 = *(const bf16x8*)(&qr_bf[lr * PADC + (w * 2 + 1) * HD + lg * 8]);

        f32x4 acc[4];
#pragma unroll
        for (int ct = 0; ct < 4; ++ct) {
            const int head = w * 2 + (ct >> 1);
            const int cl   = (ct & 1) * 16 + lr;
            const bf16x8 bf = *(const bf16x8*)(kvbT +
                (((size_t)b * NHEAD + head) * HD + cl) * HD + lg * 8);
            f32x4 z4 = {0.f, 0.f, 0.f, 0.f};
            acc[ct] = __builtin_amdgcn_mfma_f32_16x16x32_bf16(
                (ct < 2) ? af0 : af1, bf, z4, 0, 0, 0);
        }
#pragma unroll
        for (int ct = 0; ct < 4; ++ct) {
            const int c = (w * 2 + (ct >> 1)) * HD + (ct & 1) * 16 + lr;
#pragma unroll
            for (int r = 0; r < 4; ++r)
                attn_lds[lg * 4 + r][c] = acc[ct][r];
        }
    }

    __syncthreads();

    // ---- epilogue: lepe (registers already loaded) + attn + store ----
    float* ob = out + ((size_t)b * NN + (size_t)irow * 64 + j0) * CC + t;
#pragma unroll
    for (int tt = 0; tt < 2; ++tt) {
#pragma unroll
        for (int q = 0; q < 8; ++q) {
            const int jl = tt * 8 + q;          // local pixel 0..15
            float lepe = bias
                + wreg[0] * cu[tt][q] + wreg[1] * cu[tt][q + 1] + wreg[2] * cu[tt][q + 2]
                + wreg[3] * cm[tt][q] + wreg[4] * cm[tt][q + 1] + wreg[5] * cm[tt][q + 2]
                + wreg[6] * cd[tt][q] + wreg[7] * cd[tt][q + 1] + wreg[8] * cd[tt][q + 2];
            __builtin_nontemporal_store(attn_lds[jl][t] + lepe, ob + (long)jl * CC);
        }
    }
}

extern "C" void kernel_launch(void* const* d_in, const int* in_sizes, int n_in,
                              void* d_out, int out_size, void* d_ws, size_t ws_size,
                              hipStream_t stream) {
    const float* x1   = (const float*)d_in[0];
    const float* x2   = (const float*)d_in[1];
    const float* x3   = (const float*)d_in[2];
    const float* posw = (const float*)d_in[3];
    const float* lw   = (const float*)d_in[4];
    const float* lb   = (const float*)d_in[5];
    float* out = (float*)d_out;

    // ws layout: pw | pkv | pksum | kmean | kvbT(ushort)  (~21.6 MB)
    const size_t pw_sz = (size_t)NN * CC;                   // 1M floats
    float* pwb   = (float*)d_ws;
    float* pkv   = pwb + pw_sz;                             // 16*NCH * 8192
    float* pksum = pkv + (size_t)16 * NCH * 8192;           // 16*NCH * 256
    float* kmean = pksum + (size_t)16 * NCH * 256;          // 16 * 256
    unsigned short* kvbT = (unsigned short*)(kmean + (size_t)16 * 256);  // 16*8192

    k0_pw<<<1024, 256, 0, stream>>>(posw, pwb);
    k1_partial<<<BB * NCH, 512, 0, stream>>>(x2, x3, pwb, pkv, pksum);
    k2_reduce<<<512, 256, 0, stream>>>(pkv, pksum, kvbT, kmean);
    k3_out<<<BB * 256, 256, 0, stream>>>(x1, x3, pwb, kvbT, kmean, lw, lb, out);
}

// Round 12
// 84.736 us; speedup vs baseline: 1.3697x; 1.0488x over previous
//
#include <hip/hip_runtime.h>

#define BB 16
#define HIMG 64
#define WIMG 64
#define CC 256
#define NHEAD 8
#define HD 32
#define NN 4096
#define PWD 65   // 2*DH+1
#define PADC 264 // qr_bf row stride (ushorts)
#define NCH 32   // k1 chunks per batch (128 rows each)
#define TSTR 66  // transpose-LDS row stride (ushorts): 132B -> conflict-free writes

typedef short bf16x8 __attribute__((ext_vector_type(8)));
typedef float f32x4 __attribute__((ext_vector_type(4)));

__device__ __forceinline__ float elu1(float x) {
    return x > 0.0f ? x + 1.0f : __expf(x);
}
__device__ __forceinline__ float sigm(float x) {
    return 1.0f / (1.0f + __expf(-x));
}
__device__ __forceinline__ unsigned short f2bf(float f) {
    union { float f; unsigned int u; } v; v.f = f;
    unsigned int r = v.u + 0x7FFFu + ((v.u >> 16) & 1u);   // RNE
    return (unsigned short)(r >> 16);
}

// ---------------- Kernel 0: pw[n][c] = sigmoid(posw[i+1][j+1][c]) ---------------
__global__ __launch_bounds__(256) void k0_pw(
    const float* __restrict__ posw, float* __restrict__ pw)
{
    const int gid = blockIdx.x * 256 + threadIdx.x;  // 0 .. 262143
    const int n = gid >> 6;
    const int p = gid & 63;
    const int ii = n >> 6, jj = n & 63;
    const float4 v = *(const float4*)(posw + (size_t)((ii + 1) * PWD + (jj + 1)) * CC + p * 4);
    float4 r;
    r.x = sigm(v.x); r.y = sigm(v.y); r.z = sigm(v.z); r.w = sigm(v.w);
    *(float4*)(pw + (size_t)n * CC + p * 4) = r;
}

// ---------------- Kernel 1: partial kv via wave-private MFMA, no barriers -------
// grid = 1024 x 256 (4 waves). Wave -> (b, head, 128-row chunk). Per 64-row slab:
// 24 coalesced float4 loads (k, pw, v; 8x128B segments each), elu+gate -> bf16,
// transpose-stage to private LDS [d][n]/[e][n], 8x mfma_16x16x32_bf16.
// ksum accumulated in exact f32, cross-lane shfl reduce. Zero __syncthreads.
__global__ __launch_bounds__(256, 2) void k1_partial(
    const float* __restrict__ x2, const float* __restrict__ x3,
    const float* __restrict__ pw, float* __restrict__ pkv,
    float* __restrict__ pksum)
{
    __shared__ unsigned short krT[4][HD][TSTR];   // 16.5 KiB
    __shared__ unsigned short vT[4][HD][TSTR];    // 16.5 KiB

    const int t     = threadIdx.x;
    const int wv    = t >> 6;
    const int gw    = blockIdx.x * 4 + wv;   // 0..4095
    const int b     = gw >> 8;
    const int rem   = gw & 255;
    const int h     = rem >> 5;
    const int chunk = rem & 31;
    const int n0    = chunk * 128;
    const int l     = t & 63;
    const int r8    = l >> 3;      // row-within-8
    const int cq    = l & 7;       // channel quad

    const float* x2b = x2 + (size_t)b * NN * CC + h * HD + cq * 4;
    const float* x3b = x3 + (size_t)b * NN * CC + h * HD + cq * 4;
    const float* pwb = pw + h * HD + cq * 4;

    f32x4 a00 = {0.f,0.f,0.f,0.f}, a01 = {0.f,0.f,0.f,0.f};
    f32x4 a10 = {0.f,0.f,0.f,0.f}, a11 = {0.f,0.f,0.f,0.f};
    float ks0 = 0.f, ks1 = 0.f, ks2 = 0.f, ks3 = 0.f;

    float4 kx[8], pv[8], vx[8];

#define K1_ISSUE(sl)                                                          \
    do {                                                                      \
        _Pragma("unroll")                                                     \
        for (int i = 0; i < 8; ++i) {                                         \
            const size_t n_ = (size_t)(n0 + (sl) * 64 + i * 8 + r8) * CC;     \
            kx[i] = *(const float4*)(x2b + n_);                               \
        }                                                                     \
        _Pragma("unroll")                                                     \
        for (int i = 0; i < 8; ++i) {                                         \
            const size_t n_ = (size_t)(n0 + (sl) * 64 + i * 8 + r8) * CC;     \
            pv[i] = *(const float4*)(pwb + n_);                               \
        }                                                                     \
        _Pragma("unroll")                                                     \
        for (int i = 0; i < 8; ++i) {                                         \
            const size_t n_ = (size_t)(n0 + (sl) * 64 + i * 8 + r8) * CC;     \
            vx[i] = *(const float4*)(x3b + n_);                               \
        }                                                                     \
    } while (0)

#define K1_SLAB(PREF)                                                         \
    do {                                                                      \
        _Pragma("unroll")                                                     \
        for (int i = 0; i < 8; ++i) {                                         \
            const int nl = i * 8 + r8;                                        \
            const float e0 = elu1(kx[i].x), e1 = elu1(kx[i].y);               \
            const float e2 = elu1(kx[i].z), e3 = elu1(kx[i].w);               \
            ks0 += e0; ks1 += e1; ks2 += e2; ks3 += e3;                       \
            krT[wv][cq * 4 + 0][nl] = f2bf(e0 * pv[i].x);                     \
            krT[wv][cq * 4 + 1][nl] = f2bf(e1 * pv[i].y);                     \
            krT[wv][cq * 4 + 2][nl] = f2bf(e2 * pv[i].z);                     \
            krT[wv][cq * 4 + 3][nl] = f2bf(e3 * pv[i].w);                     \
            vT[wv][cq * 4 + 0][nl] = f2bf(vx[i].x);                           \
            vT[wv][cq * 4 + 1][nl] = f2bf(vx[i].y);                           \
            vT[wv][cq * 4 + 2][nl] = f2bf(vx[i].z);                           \
            vT[wv][cq * 4 + 3][nl] = f2bf(vx[i].w);                           \
        }                                                                     \
        if (PREF) K1_ISSUE(1);                                                \
        _Pragma("unroll")                                                     \
        for (int kc = 0; kc < 2; ++kc) {                                      \
            const int ko = kc * 32 + (l >> 4) * 8;                            \
            union { bf16x8 v8; ushort2 u2[4]; } fa0, fa1, fb0, fb1;           \
            _Pragma("unroll")                                                 \
            for (int j = 0; j < 4; ++j) {                                     \
                fa0.u2[j] = *(const ushort2*)&krT[wv][l & 15][ko + j * 2];    \
                fa1.u2[j] = *(const ushort2*)&krT[wv][16 + (l & 15)][ko + j * 2]; \
                fb0.u2[j] = *(const ushort2*)&vT[wv][l & 15][ko + j * 2];     \
                fb1.u2[j] = *(const ushort2*)&vT[wv][16 + (l & 15)][ko + j * 2];  \
            }                                                                 \
            a00 = __builtin_amdgcn_mfma_f32_16x16x32_bf16(fa0.v8, fb0.v8, a00, 0, 0, 0); \
            a01 = __builtin_amdgcn_mfma_f32_16x16x32_bf16(fa0.v8, fb1.v8, a01, 0, 0, 0); \
            a10 = __builtin_amdgcn_mfma_f32_16x16x32_bf16(fa1.v8, fb0.v8, a10, 0, 0, 0); \
            a11 = __builtin_amdgcn_mfma_f32_16x16x32_bf16(fa1.v8, fb1.v8, a11, 0, 0, 0); \
        }                                                                     \
    } while (0)

    K1_ISSUE(0);
    K1_SLAB(1);     // slab 0; prefetch slab 1 between convert and MFMA
    K1_SLAB(0);     // slab 1

#undef K1_ISSUE
#undef K1_SLAB

    // ---- store kv partial in MFMA-native layout: o = h*1024 + tile*256 + l*4+reg
    float* dst = pkv + (size_t)(b * NCH + chunk) * (NHEAD * HD * HD) + h * (HD * HD);
    *(f32x4*)(dst + 0 * 256 + l * 4) = a00;   // tile (dt=0,et=0)
    *(f32x4*)(dst + 1 * 256 + l * 4) = a01;   // tile (dt=0,et=1)
    *(f32x4*)(dst + 2 * 256 + l * 4) = a10;   // tile (dt=1,et=0)
    *(f32x4*)(dst + 3 * 256 + l * 4) = a11;   // tile (dt=1,et=1)

    // ---- ksum: reduce over row-lanes (l bits 3..5), lanes 0..7 hold channel quads
    ks0 += __shfl_xor(ks0, 8);  ks1 += __shfl_xor(ks1, 8);
    ks2 += __shfl_xor(ks2, 8);  ks3 += __shfl_xor(ks3, 8);
    ks0 += __shfl_xor(ks0, 16); ks1 += __shfl_xor(ks1, 16);
    ks2 += __shfl_xor(ks2, 16); ks3 += __shfl_xor(ks3, 16);
    ks0 += __shfl_xor(ks0, 32); ks1 += __shfl_xor(ks1, 32);
    ks2 += __shfl_xor(ks2, 32); ks3 += __shfl_xor(ks3, 32);
    if (l < 8) {
        float4 o4 = {ks0, ks1, ks2, ks3};
        *(float4*)(pksum + (size_t)(b * NCH + chunk) * CC + h * HD + l * 4) = o4;
    }
}

// ---------------- Kernel 2: reduce partials; emit kvbT (bf16, [b][h][e][d]) -----
// grid = 512, block = 256. pkv o-layout is MFMA-native: h*1024 + tile*256 + l*4+r.
__global__ __launch_bounds__(256) void k2_reduce(
    const float* __restrict__ pkv, const float* __restrict__ pksum,
    unsigned short* __restrict__ kvbT, float* __restrict__ kmean)
{
    const int gid = blockIdx.x * 256 + threadIdx.x;   // over B*8192
    const int b = gid >> 13;
    const int o = gid & 8191;
    float s = 0.f;
#pragma unroll 4
    for (int c = 0; c < NCH; ++c)
        s += pkv[(size_t)(b * NCH + c) * (NHEAD * HD * HD) + o];
    const int hh   = o >> 10;
    const int r1   = o & 1023;
    const int tile = r1 >> 8;
    const int li   = (r1 >> 2) & 63;
    const int rg   = o & 3;
    const int d    = (tile >> 1) * 16 + (li >> 4) * 4 + rg;
    const int e    = (tile & 1) * 16 + (li & 15);
    kvbT[(((size_t)b * NHEAD + hh) * HD + e) * HD + d] = f2bf(s * (1.0f / NN));
    if (o < CC) {
        float ss = 0.f;
#pragma unroll 4
        for (int c = 0; c < NCH; ++c)
            ss += pksum[(size_t)(b * NCH + c) * CC + o];
        kmean[b * CC + o] = ss * (1.0f / NN);
    }
}

// ---------------- Kernel 3: out = MFMA((qr*z) @ kv) + LePE ----------------------
// grid = B*256 (quarter image row each), block = 256 (4 waves)
__global__ __launch_bounds__(256, 2) void k3_out(
    const float* __restrict__ x1, const float* __restrict__ x3,
    const float* __restrict__ pw, const unsigned short* __restrict__ kvbT,
    const float* __restrict__ kmean, const float* __restrict__ lw,
    const float* __restrict__ lb, float* __restrict__ out)
{
    const int blk  = blockIdx.x;      // b*256 + irow*4 + jq
    const int b    = blk >> 8;
    const int irow = (blk >> 2) & 63;
    const int jq   = blk & 3;
    const int j0   = jq << 4;         // 0, 16, 32, 48
    const int t    = threadIdx.x;

    __shared__ unsigned short qr_bf[16 * PADC];   // (qr * z) in bf16, 8.4 KiB
    __shared__ float attn_lds[16][CC];            // 16 KiB

    float wreg[9];
#pragma unroll
    for (int q = 0; q < 9; ++q) wreg[q] = lw[t * 9 + q];
    const float bias = lb[t];

    // ---- stage: q_rope * z  -> bf16 LDS (z folded in; known after shfl reduce) ----
    {
        const int p    = t & 63;       // float4 slot within a pixel's 256 channels
        const int pixo = t >> 6;       // 0..3
        const float4 km4 = *(const float4*)(kmean + b * CC + p * 4);
        const float* x1b = x1 + ((size_t)b * NN + (size_t)irow * 64 + j0) * CC;
        const float* pwb = pw + ((size_t)irow * 64 + j0) * CC;
        float4 xv[4], pvv[4];
#pragma unroll
        for (int s = 0; s < 4; ++s)
            xv[s] = *(const float4*)(x1b + (size_t)(s * 4 + pixo) * CC + p * 4);
#pragma unroll
        for (int s = 0; s < 4; ++s)
            pvv[s] = *(const float4*)(pwb + (size_t)(s * 4 + pixo) * CC + p * 4);
#pragma unroll
        for (int s = 0; s < 4; ++s) {
            const int pix = s * 4 + pixo;   // 0..15 (local)
            float4 q4;
            q4.x = elu1(xv[s].x); q4.y = elu1(xv[s].y);
            q4.z = elu1(xv[s].z); q4.w = elu1(xv[s].w);
            float zp = q4.x * km4.x + q4.y * km4.y + q4.z * km4.z + q4.w * km4.w;
            zp += __shfl_xor(zp, 1);
            zp += __shfl_xor(zp, 2);
            zp += __shfl_xor(zp, 4);        // all 8 lanes of this head have the sum
            const float zin = 1.0f / (zp + 1e-6f);
            ushort4 u;
            u.x = f2bf(q4.x * pvv[s].x * zin);
            u.y = f2bf(q4.y * pvv[s].y * zin);
            u.z = f2bf(q4.z * pvv[s].z * zin);
            u.w = f2bf(q4.w * pvv[s].w * zin);
            *(ushort4*)(&qr_bf[pix * PADC + p * 4]) = u;
        }
    }

    // ---- halo loads issued BEFORE the barrier: cannot be sunk past it ----
    const bool hasU = irow > 0, hasD = irow < 63;
    const float* rU = x3 + ((size_t)b * NN + (size_t)(irow - 1) * 64 + j0) * CC + t;
    const float* rM = x3 + ((size_t)b * NN + (size_t)irow * 64 + j0) * CC + t;
    const float* rD = x3 + ((size_t)b * NN + (size_t)(irow + 1) * 64 + j0) * CC + t;

    float cu[2][10], cm[2][10], cd[2][10];
#pragma unroll
    for (int tt = 0; tt < 2; ++tt)
#pragma unroll
        for (int q = 0; q < 10; ++q) {
            const int col = tt * 8 + q - 1;     // local col in [-1, 16]
            const int g   = j0 + col;           // global col in [-1, 64]
            const bool ok = (g >= 0) && (g < 64);
            const long off = (long)col * CC;
            cm[tt][q] = ok ? rM[off] : 0.f;
            cu[tt][q] = (ok && hasU) ? rU[off] : 0.f;
            cd[tt][q] = (ok && hasD) ? rD[off] : 0.f;
        }

    __syncthreads();

    // ---- MFMA phase: wave w covers heads 2w,2w+1 over all 16 pixels ----
    {
        const int w  = t >> 6;
        const int l  = t & 63;
        const int lr = l & 15;     // A row (pixel) / B col / D col
        const int lg = l >> 4;     // k-group

        bf16x8 af0 = *(const bf16x8*)(&qr_bf[lr * PADC + (w * 2 + 0) * HD + lg * 8]);
        bf16x8 af1 = *(const bf16x8*)(&qr_bf[lr * PADC + (w * 2 + 1) * HD + lg * 8]);

        f32x4 acc[4];
#pragma unroll
        for (int ct = 0; ct < 4; ++ct) {
            const int head = w * 2 + (ct >> 1);
            const int cl   = (ct & 1) * 16 + lr;
            const bf16x8 bf = *(const bf16x8*)(kvbT +
                (((size_t)b * NHEAD + head) * HD + cl) * HD + lg * 8);
            f32x4 z4 = {0.f, 0.f, 0.f, 0.f};
            acc[ct] = __builtin_amdgcn_mfma_f32_16x16x32_bf16(
                (ct < 2) ? af0 : af1, bf, z4, 0, 0, 0);
        }
#pragma unroll
        for (int ct = 0; ct < 4; ++ct) {
            const int c = (w * 2 + (ct >> 1)) * HD + (ct & 1) * 16 + lr;
#pragma unroll
            for (int r = 0; r < 4; ++r)
                attn_lds[lg * 4 + r][c] = acc[ct][r];
        }
    }

    __syncthreads();

    // ---- epilogue: lepe (registers already loaded) + attn + store ----
    float* ob = out + ((size_t)b * NN + (size_t)irow * 64 + j0) * CC + t;
#pragma unroll
    for (int tt = 0; tt < 2; ++tt) {
#pragma unroll
        for (int q = 0; q < 8; ++q) {
            const int jl = tt * 8 + q;          // local pixel 0..15
            float lepe = bias
                + wreg[0] * cu[tt][q] + wreg[1] * cu[tt][q + 1] + wreg[2] * cu[tt][q + 2]
                + wreg[3] * cm[tt][q] + wreg[4] * cm[tt][q + 1] + wreg[5] * cm[tt][q + 2]
                + wreg[6] * cd[tt][q] + wreg[7] * cd[tt][q + 1] + wreg[8] * cd[tt][q + 2];
            __builtin_nontemporal_store(attn_lds[jl][t] + lepe, ob + (long)jl * CC);
        }
    }
}

extern "C" void kernel_launch(void* const* d_in, const int* in_sizes, int n_in,
                              void* d_out, int out_size, void* d_ws, size_t ws_size,
                              hipStream_t stream) {
    const float* x1   = (const float*)d_in[0];
    const float* x2   = (const float*)d_in[1];
    const float* x3   = (const float*)d_in[2];
    const float* posw = (const float*)d_in[3];
    const float* lw   = (const float*)d_in[4];
    const float* lb   = (const float*)d_in[5];
    float* out = (float*)d_out;

    // ws layout: pw | pkv | pksum | kmean | kvbT(ushort)  (~21.6 MB)
    const size_t pw_sz = (size_t)NN * CC;                   // 1M floats
    float* pwb   = (float*)d_ws;
    float* pkv   = pwb + pw_sz;                             // 16*NCH * 8192
    float* pksum = pkv + (size_t)16 * NCH * 8192;           // 16*NCH * 256
    float* kmean = pksum + (size_t)16 * NCH * 256;          // 16 * 256
    unsigned short* kvbT = (unsigned short*)(kmean + (size_t)16 * 256);  // 16*8192

    k0_pw<<<1024, 256, 0, stream>>>(posw, pwb);
    k1_partial<<<BB * NHEAD * NCH / 4, 256, 0, stream>>>(x2, x3, pwb, pkv, pksum);
    k2_reduce<<<512, 256, 0, stream>>>(pkv, pksum, kvbT, kmean);
    k3_out<<<BB * 256, 256, 0, stream>>>(x1, x3, pwb, kvbT, kmean, lw, lb, out);
}